// Round 2
// baseline (121.656 us; speedup 1.0000x reference)
//
#include <hip/hip_runtime.h>
#include <math.h>

#define B_MOL 64
#define A_MAX 48
#define NSPEC 4
#define NRS2 24
#define NRS3 20
#define NPAIRS 10
#define REP2 (NSPEC * NRS2)        // 96
#define REP3 (NPAIRS * NRS3 * 2)   // 400
#define REPTOT (REP2 + REP3)       // 496

#define RCUT_F 6.0f
#define ETA2_F 0.32f
#define ETA3_F 2.7f
#define PI_F 3.14159265358979323846f
#define W3_F 12.4225780586f        // sqrt(2.7/pi)*13.4
#define SQRT_2PI_F 2.5066282746310002f

#define WPB 2                      // waves (= atoms) per block

// closed-form triplet decode: t -> (a, c), a < c < m, row-major over a
__device__ __forceinline__ void decode_tri(int t, int m, int& a_out, int& c_out) {
    const float fm = (float)(2 * m - 1);
    const float disc = fm * fm - 8.0f * (float)t;   // <= 8649, integer-exact in f32
    const float sq = __builtin_amdgcn_sqrtf(disc);
    int a = (int)((fm - sq) * 0.5f);
    if (a < 0) a = 0;
    while (a > 0 && (a * (2 * m - 1 - a)) / 2 > t) --a;
    while (((a + 1) * (2 * m - 1 - (a + 1))) / 2 <= t) ++a;
    a_out = a;
    c_out = t - (a * (2 * m - 1 - a)) / 2 + a + 1;
}

// One wave (64 lanes) per atom, 2 atoms per 128-thread block.
// Per-atom LDS ~3.7 KB (vs 17.5 KB in the 256-thread version): no triplet
// staging arrays, no bucket sort. rep3 is accumulated directly via LDS float
// atomics with an l-stagger so lanes sharing a pair-species p mostly hit
// different addresses.
// __launch_bounds__(128,6): 12 blocks/CU = 24 resident atoms (vs 8 before),
// LDS 12*7.5KB = 90KB < 160KB, VGPR budget ~80 (no spill).
__global__ __launch_bounds__(64 * WPB, 6) void fchl_kernel(
    const float* __restrict__ X, const int* __restrict__ Z,
    const int* __restrict__ atom_counts, float* __restrict__ out)
{
    __shared__ float nb_dx[WPB][A_MAX], nb_dy[WPB][A_MAX], nb_dz[WPB][A_MAX];
    __shared__ float nb_r[WPB][A_MAX], nb_r2[WPB][A_MAX], nb_rinv[WPB][A_MAX];
    __shared__ float nb_fc[WPB][A_MAX], nb_mu[WPB][A_MAX];
    __shared__ float nb_i2s2[WPB][A_MAX], nb_pref[WPB][A_MAX];
    __shared__ int   nb_z[WPB][A_MAX];
    __shared__ float acc3[WPB][REP3];            // per-wave 3-body accumulator

    const int wv   = threadIdx.x >> 6;           // which atom of this block
    const int lane = threadIdx.x & 63;
    const int bi   = blockIdx.x * WPB + wv;      // b*A_MAX + i
    const int b = bi / A_MAX;
    const int i = bi % A_MAX;
    const int cnt = atom_counts[b];
    float* orow = out + (size_t)bi * REPTOT;
    const bool active = (i < cnt);               // wave-uniform

    int m = 0;

    // ---- Phase A: wave-local ballot-compacted neighbor list ----
    if (active) {
        const float xi = X[(b * A_MAX + i) * 3 + 0];
        const float yi = X[(b * A_MAX + i) * 3 + 1];
        const float zi = X[(b * A_MAX + i) * 3 + 2];

        bool flag = false;
        float dx = 0.f, dy = 0.f, dz = 0.f, r = 1.f;
        int zj = 0;
        if (lane < A_MAX && lane < cnt) {
            dx = xi - X[(b * A_MAX + lane) * 3 + 0];
            dy = yi - X[(b * A_MAX + lane) * 3 + 1];
            dz = zi - X[(b * A_MAX + lane) * 3 + 2];
            zj = Z[b * A_MAX + lane];
            r = __builtin_amdgcn_sqrtf(dx * dx + dy * dy + dz * dz);
            flag = (lane != i) && (r < RCUT_F);
        }
        const unsigned long long mask = __ballot(flag ? 1 : 0);
        if (flag) {
            const int pos = __popcll(mask & ((1ull << lane) - 1ull));
            nb_dx[wv][pos] = dx; nb_dy[wv][pos] = dy; nb_dz[wv][pos] = dz;
            nb_r[wv][pos]  = r;  nb_r2[wv][pos] = r * r;
            nb_rinv[wv][pos] = __builtin_amdgcn_rcpf(r);
            nb_z[wv][pos]  = zj;
            const float fc = 0.5f * (__cosf(PI_F * r * (1.0f / RCUT_F)) + 1.0f);
            const float lr = __logf(r);
            const float s2 = log1pf(ETA2_F / (r * r));
            nb_fc[wv][pos]   = fc;
            nb_mu[wv][pos]   = lr - 0.5f * s2;
            nb_i2s2[wv][pos] = 0.5f * __builtin_amdgcn_rcpf(s2);
            nb_pref[wv][pos] = fc * __expf(-1.8f * lr) *
                               __builtin_amdgcn_rcpf(__builtin_amdgcn_sqrtf(s2) * SQRT_2PI_F);
        }
        m = (int)__popcll(mask);
        for (int k2 = lane; k2 < REP3; k2 += 64) acc3[wv][k2] = 0.0f;
    }
    __syncthreads();                             // barrier 1 (LDS visibility)

    if (active) {
        // ---- 2-body: 96 outputs over 64 lanes ----
        for (int t2 = lane; t2 < REP2; t2 += 64) {
            const int s = t2 / NRS2;
            const int n = t2 % NRS2;
            const float Rn = 0.25f * (float)(n + 1);   // RS2[n]
            const float logRn = __logf(Rn);
            float acc = 0.0f;
            for (int a = 0; a < m; ++a) {
                if (nb_z[wv][a] == s) {
                    const float dmu = logRn - nb_mu[wv][a];
                    acc += nb_pref[wv][a] * __expf(-dmu * dmu * nb_i2s2[wv][a]);
                }
            }
            orow[t2] = acc * __builtin_amdgcn_rcpf(Rn);
        }

        // ---- 3-body: geometry once per triplet, direct LDS accumulation ----
        const int ntrip = m * (m - 1) / 2;
        const int l0 = lane % NRS3;              // stagger: same-p lanes spread over l
        for (int t = lane; t < ntrip; t += 64) {
            int a, c;
            decode_tri(t, m, a, c);

            const float rij = nb_r[wv][a], rik = nb_r[wv][c];
            const float r2ij = nb_r2[wv][a], r2ik = nb_r2[wv][c];
            const float rinv_a = nb_rinv[wv][a], rinv_c = nb_rinv[wv][c];
            const float djx = nb_dx[wv][a], djy = nb_dy[wv][a], djz = nb_dz[wv][a];
            const float dkx = nb_dx[wv][c], dky = nb_dy[wv][c], dkz = nb_dz[wv][c];

            float cosi = (djx * dkx + djy * dky + djz * dkz) * rinv_a * rinv_c;
            cosi = fminf(1.0f, fmaxf(-1.0f, cosi));

            // REFERENCE SEMANTICS: r_jk clamps to 1.0 when (j,k) not within cutoff
            const float ex = dkx - djx, ey = dky - djy, ez = dkz - djz;
            const float rjk2 = ex * ex + ey * ey + ez * ez;
            const float rjk = __builtin_amdgcn_sqrtf(rjk2);
            const bool w_jk = (rjk < RCUT_F);
            const float rjke  = w_jk ? rjk : 1.0f;
            const float rjke2 = w_jk ? rjk2 : 1.0f;
            const float rinv_jk = w_jk ? __builtin_amdgcn_rcpf(rjk) : 1.0f;

            const float cosj = (r2ij + rjke2 - r2ik) * 0.5f * rinv_a * rinv_jk;
            const float cosk = (r2ik + rjke2 - r2ij) * 0.5f * rinv_c * rinv_jk;

            const float ksi = W3_F * (1.0f + 3.0f * cosi * cosj * cosk)
                            * __expf(-0.57f * __logf(rij * rik * rjke));
            const float w  = ksi * nb_fc[wv][a] * nb_fc[wv][c];
            const float wc = w * cosi;
            const float s1 = fmaxf(1.0f - cosi * cosi, 0.0f);
            const float ws = w * __builtin_amdgcn_sqrtf(s1);
            const float d  = 0.5f * (rij + rik);

            const int zj = nb_z[wv][a], zk = nb_z[wv][c];
            const int pmn = min(zj, zk), pmx = max(zj, zk);
            const int p = (pmn * (2 * NSPEC - pmn - 1)) / 2 + pmx;
            float* accp = &acc3[wv][p * (NRS3 * 2)];

            int l = l0;
            for (int it = 0; it < NRS3; ++it) {
                const float Rl = 0.3f * (float)(l + 1);   // RS3[l]
                const float dd = d - Rl;
                const float rad = __expf(-ETA3_F * dd * dd);
                atomicAdd(&accp[2 * l + 0], wc * rad);
                atomicAdd(&accp[2 * l + 1], ws * rad);
                l = (l + 1 == NRS3) ? 0 : l + 1;
            }
        }
    } else {
        // invalid atom: zero the whole row (matches reference padding)
        for (int k2 = lane; k2 < REPTOT; k2 += 64) orow[k2] = 0.0f;
    }
    __syncthreads();                             // barrier 2: drain ds_adds

    if (active) {
        for (int k2 = lane; k2 < REP3; k2 += 64)
            orow[REP2 + k2] = acc3[wv][k2];
    }
}

extern "C" void kernel_launch(void* const* d_in, const int* in_sizes, int n_in,
                              void* d_out, int out_size, void* d_ws, size_t ws_size,
                              hipStream_t stream) {
    const float* X           = (const float*)d_in[0];
    const int*   Z           = (const int*)d_in[1];
    // d_in[2] = atomIDs, d_in[3] = molIDs (unused by reference math)
    const int*   atom_counts = (const int*)d_in[4];
    float* out = (float*)d_out;

    fchl_kernel<<<(B_MOL * A_MAX) / WPB, 64 * WPB, 0, stream>>>(X, Z, atom_counts, out);
}

// Round 3
// 84.998 us; speedup vs baseline: 1.4313x; 1.4313x over previous
//
#include <hip/hip_runtime.h>
#include <math.h>

#define B_MOL 64
#define A_MAX 48
#define NSPEC 4
#define NRS2 24
#define NRS3 20
#define NPAIRS 10
#define REP2 (NSPEC * NRS2)        // 96
#define REP3 (NPAIRS * NRS3 * 2)   // 400
#define REPTOT (REP2 + REP3)       // 496
#define TRIP_CAP 1084              // >= 47*46/2 = 1081

#define RCUT_F 6.0f
#define ETA2_F 0.32f
#define ETA3_F 2.7f
#define PI_F 3.14159265358979323846f
#define W3_F 12.4225780586f        // sqrt(2.7/pi)*13.4
#define SQRT_2PI_F 2.5066282746310002f

// closed-form triplet decode: t -> (a, c), a < c < m, row-major over a
__device__ __forceinline__ void decode_tri(int t, int m, int& a_out, int& c_out) {
    const float fm = (float)(2 * m - 1);
    const float disc = fm * fm - 8.0f * (float)t;   // <= 8649, integer-exact in f32
    const float sq = __builtin_amdgcn_sqrtf(disc);
    int a = (int)((fm - sq) * 0.5f);
    if (a < 0) a = 0;
    while (a > 0 && (a * (2 * m - 1 - a)) / 2 > t) --a;
    while (((a + 1) * (2 * m - 1 - (a + 1))) / 2 <= t) ++a;
    a_out = a;
    c_out = t - (a * (2 * m - 1 - a)) / 2 + a + 1;
}

// One wave (64 threads) per atom. Atomic-free 3-body reduction:
//   B1: geometry ONCE per triplet -> trip_{wc,ws,d}[t]; 1 LDS atomic counts bucket p.
//   B2: sorted INDEX build: sidx[bstart[p]+q] = t  (payload stays unsorted).
//   C:  200 (p,l) pairs spread as e = lane+64k -> each lane walks ~3.3 mixed
//       buckets (balanced), accumulating in registers. Zero accumulation atomics.
// LDS 19.5 KB/block -> 8 blocks/CU resident. Barriers are single-wave (cheap).
__global__ __launch_bounds__(64, 4) void fchl_kernel(
    const float* __restrict__ X, const int* __restrict__ Z,
    const int* __restrict__ atom_counts, float* __restrict__ out)
{
    __shared__ float nb_dx[A_MAX], nb_dy[A_MAX], nb_dz[A_MAX];
    __shared__ float nb_r[A_MAX], nb_r2[A_MAX], nb_rinv[A_MAX];
    __shared__ float nb_fc[A_MAX], nb_mu[A_MAX], nb_i2s2[A_MAX], nb_pref[A_MAX];
    __shared__ int   nb_z[A_MAX];
    __shared__ float trip_wc[TRIP_CAP], trip_ws[TRIP_CAP], trip_d[TRIP_CAP];
    __shared__ unsigned short pq[TRIP_CAP];      // p | (rank<<4)
    __shared__ unsigned short sidx[TRIP_CAP];    // bucket-sorted triplet index
    __shared__ int bcnt[NPAIRS], bstart[NPAIRS];

    const int bi = blockIdx.x;                   // b*A_MAX + i
    const int b = bi / A_MAX;
    const int i = bi % A_MAX;
    const int lane = threadIdx.x;                // 0..63
    const int cnt = atom_counts[b];
    float* orow = out + (size_t)bi * REPTOT;

    // whole-block early exit for padded atoms (block-uniform, before any barrier)
    if (i >= cnt) {
        for (int t = lane; t < REPTOT; t += 64) orow[t] = 0.0f;
        return;
    }

    if (lane < NPAIRS) bcnt[lane] = 0;

    // ---- Phase A: wave-local ballot-compacted neighbor list ----
    const float xi = X[(b * A_MAX + i) * 3 + 0];
    const float yi = X[(b * A_MAX + i) * 3 + 1];
    const float zi = X[(b * A_MAX + i) * 3 + 2];

    bool flag = false;
    {
        float dx = 0.f, dy = 0.f, dz = 0.f, r = 1.f;
        int zj = 0;
        if (lane < A_MAX && lane < cnt) {
            dx = xi - X[(b * A_MAX + lane) * 3 + 0];
            dy = yi - X[(b * A_MAX + lane) * 3 + 1];
            dz = zi - X[(b * A_MAX + lane) * 3 + 2];
            zj = Z[b * A_MAX + lane];
            r = __builtin_amdgcn_sqrtf(dx * dx + dy * dy + dz * dz);
            flag = (lane != i) && (r < RCUT_F);
        }
        const unsigned long long mask = __ballot(flag ? 1 : 0);
        if (flag) {
            const int pos = __popcll(mask & ((1ull << lane) - 1ull));
            nb_dx[pos] = dx; nb_dy[pos] = dy; nb_dz[pos] = dz;
            nb_r[pos]  = r;  nb_r2[pos] = r * r;
            nb_rinv[pos] = __builtin_amdgcn_rcpf(r);
            nb_z[pos]  = zj;
            const float fc = 0.5f * (__cosf(PI_F * r * (1.0f / RCUT_F)) + 1.0f);
            const float lr = __logf(r);
            const float s2 = log1pf(ETA2_F / (r * r));
            nb_fc[pos]   = fc;
            nb_mu[pos]   = lr - 0.5f * s2;
            nb_i2s2[pos] = 0.5f * __builtin_amdgcn_rcpf(s2);
            nb_pref[pos] = fc * __expf(-1.8f * lr) *
                           __builtin_amdgcn_rcpf(__builtin_amdgcn_sqrtf(s2) * SQRT_2PI_F);
        }
    }
    const int m = (int)__popcll(__ballot(flag ? 1 : 0));
    __syncthreads();                             // barrier 1: nb_* visible

    // ---- 2-body: 96 outputs over 64 lanes (broadcast reads of nb_*) ----
    for (int t2 = lane; t2 < REP2; t2 += 64) {
        const int s = t2 / NRS2;
        const int n = t2 % NRS2;
        const float Rn = 0.25f * (float)(n + 1);   // RS2[n]
        const float logRn = __logf(Rn);
        float acc = 0.0f;
        for (int a = 0; a < m; ++a) {
            if (nb_z[a] == s) {
                const float dmu = logRn - nb_mu[a];
                acc += nb_pref[a] * __expf(-dmu * dmu * nb_i2s2[a]);
            }
        }
        orow[t2] = acc * __builtin_amdgcn_rcpf(Rn);
    }

    // ---- Phase B1: geometry ONCE per triplet + bucket count ----
    const int ntrip = m * (m - 1) / 2;
    for (int t = lane; t < ntrip; t += 64) {
        int a, c;
        decode_tri(t, m, a, c);

        const float rij = nb_r[a], rik = nb_r[c];
        const float r2ij = nb_r2[a], r2ik = nb_r2[c];
        const float rinv_a = nb_rinv[a], rinv_c = nb_rinv[c];
        const float djx = nb_dx[a], djy = nb_dy[a], djz = nb_dz[a];
        const float dkx = nb_dx[c], dky = nb_dy[c], dkz = nb_dz[c];

        float cosi = (djx * dkx + djy * dky + djz * dkz) * rinv_a * rinv_c;
        cosi = fminf(1.0f, fmaxf(-1.0f, cosi));

        // REFERENCE SEMANTICS: r_jk clamps to 1.0 when (j,k) not within cutoff
        const float ex = dkx - djx, ey = dky - djy, ez = dkz - djz;
        const float rjk2 = ex * ex + ey * ey + ez * ez;
        const float rjk = __builtin_amdgcn_sqrtf(rjk2);
        const bool w_jk = (rjk < RCUT_F);
        const float rjke  = w_jk ? rjk : 1.0f;
        const float rjke2 = w_jk ? rjk2 : 1.0f;
        const float rinv_jk = w_jk ? __builtin_amdgcn_rcpf(rjk) : 1.0f;

        const float cosj = (r2ij + rjke2 - r2ik) * 0.5f * rinv_a * rinv_jk;
        const float cosk = (r2ik + rjke2 - r2ij) * 0.5f * rinv_c * rinv_jk;

        const float ksi = W3_F * (1.0f + 3.0f * cosi * cosj * cosk)
                        * __expf(-0.57f * __logf(rij * rik * rjke));
        const float w  = ksi * nb_fc[a] * nb_fc[c];
        const float s1 = fmaxf(1.0f - cosi * cosi, 0.0f);

        trip_wc[t] = w * cosi;
        trip_ws[t] = w * __builtin_amdgcn_sqrtf(s1);
        trip_d[t]  = 0.5f * (rij + rik);

        const int zj = nb_z[a], zk = nb_z[c];
        const int pmn = min(zj, zk), pmx = max(zj, zk);
        const int p = (pmn * (2 * NSPEC - pmn - 1)) / 2 + pmx;
        const int q = atomicAdd(&bcnt[p], 1);    // ONE atomic per triplet
        pq[t] = (unsigned short)(p | (q << 4));
    }
    __syncthreads();                             // barrier 2: counts + payload visible
    if (lane < NPAIRS) {                         // tiny exclusive prefix
        int s = 0;
        for (int p = 0; p < lane; ++p) s += bcnt[p];
        bstart[lane] = s;
    }
    __syncthreads();                             // barrier 3

    // ---- Phase B2: build sorted index (payload stays in place) ----
    for (int t = lane; t < ntrip; t += 64) {
        const unsigned short e = pq[t];
        sidx[bstart[e & 15] + (int)(e >> 4)] = (unsigned short)t;
    }
    __syncthreads();                             // barrier 4

    // ---- Phase C: 200 (p,l) pairs over 64 lanes, register accumulation ----
    for (int e = lane; e < NPAIRS * NRS3; e += 64) {
        const int p = e / NRS3;
        const int l = e % NRS3;
        const float Rl = 0.3f * (float)(l + 1);  // RS3[l]
        const int s0 = bstart[p];
        const int s1 = s0 + bcnt[p];
        float ac = 0.0f, as_ = 0.0f;
        if (s1 > s0) {
            int idx = sidx[s0];
            for (int s = s0 + 1; s < s1; ++s) {
                const int idxn = sidx[s];        // prefetch next index
                const float dv = trip_d[idx];
                const float dd = dv - Rl;
                const float rad = __expf(-ETA3_F * dd * dd);
                ac  += trip_wc[idx] * rad;
                as_ += trip_ws[idx] * rad;
                idx = idxn;
            }
            const float dv = trip_d[idx];
            const float dd = dv - Rl;
            const float rad = __expf(-ETA3_F * dd * dd);
            ac  += trip_wc[idx] * rad;
            as_ += trip_ws[idx] * rad;
        }
        orow[REP2 + p * (NRS3 * 2) + l * 2 + 0] = ac;
        orow[REP2 + p * (NRS3 * 2) + l * 2 + 1] = as_;
    }
}

extern "C" void kernel_launch(void* const* d_in, const int* in_sizes, int n_in,
                              void* d_out, int out_size, void* d_ws, size_t ws_size,
                              hipStream_t stream) {
    const float* X           = (const float*)d_in[0];
    const int*   Z           = (const int*)d_in[1];
    // d_in[2] = atomIDs, d_in[3] = molIDs (unused by reference math)
    const int*   atom_counts = (const int*)d_in[4];
    float* out = (float*)d_out;

    fchl_kernel<<<B_MOL * A_MAX, 64, 0, stream>>>(X, Z, atom_counts, out);
}

// Round 5
// 73.575 us; speedup vs baseline: 1.6535x; 1.1553x over previous
//
#include <hip/hip_runtime.h>
#include <math.h>

#define B_MOL 64
#define A_MAX 48
#define NSPEC 4
#define NRS2 24
#define NRS3 20
#define NPAIRS 10
#define REP2 (NSPEC * NRS2)        // 96
#define REP3 (NPAIRS * NRS3 * 2)   // 400
#define REPTOT (REP2 + REP3)       // 496
#define TRIP_CAP 1084              // >= 47*46/2 = 1081

#define RCUT_F 6.0f
#define ETA2_F 0.32f
#define ETA3_F 2.7f
#define PI_F 3.14159265358979323846f
#define W3_F 12.4225780586f        // sqrt(2.7/pi)*13.4
#define SQRT_2PI_F 2.5066282746310002f

// closed-form triplet decode: t -> (a, c), a < c < m, row-major over a
__device__ __forceinline__ void decode_tri(int t, int m, int& a_out, int& c_out) {
    const float fm = (float)(2 * m - 1);
    const float disc = fm * fm - 8.0f * (float)t;   // <= 8649, integer-exact in f32
    const float sq = __builtin_amdgcn_sqrtf(disc);
    int a = (int)((fm - sq) * 0.5f);
    if (a < 0) a = 0;
    while (a > 0 && (a * (2 * m - 1 - a)) / 2 > t) --a;
    while (((a + 1) * (2 * m - 1 - (a + 1))) / 2 <= t) ++a;
    a_out = a;
    c_out = t - (a * (2 * m - 1 - a)) / 2 + a + 1;
}

// 256 threads / atom (full 32-wave/CU occupancy), ANALYTIC bucket scatter:
//   Phase A (wave 0): ballot-compacted neighbor list + per-species ballots ->
//     per-neighbor within-species index nb_si, species counts cnt_s.
//   Phase B (all): geometry ONCE per triplet; bucket p and within-bucket rank
//     computed in VALU (triangular / iu*cmax+iv formulas) -> direct scatter to
//     sorted slot. Zero atomics, no pq/sidx arrays.
//   Phase C: 200 threads = one (p,l) bucket walk each (contiguous payload,
//     ILP-2); threads 200..255 do the 96 2-body outputs concurrently.
// 2 barriers total. LDS ~15.3 KB. Bucket prefixes recomputed per-thread as
// predicated adds over named registers (no runtime-indexed array -> no scratch).
__global__ __launch_bounds__(256, 8) void fchl_kernel(
    const float* __restrict__ X, const int* __restrict__ Z,
    const int* __restrict__ atom_counts, float* __restrict__ out)
{
    __shared__ float nb_dx[A_MAX], nb_dy[A_MAX], nb_dz[A_MAX];
    __shared__ float nb_r[A_MAX], nb_r2[A_MAX], nb_rinv[A_MAX];
    __shared__ float nb_fc[A_MAX], nb_mu[A_MAX], nb_i2s2[A_MAX], nb_pref[A_MAX];
    __shared__ int   nb_z[A_MAX], nb_si[A_MAX];
    __shared__ float trip_wc[TRIP_CAP], trip_ws[TRIP_CAP], trip_d[TRIP_CAP];
    __shared__ int   cnt_s[NSPEC];
    __shared__ int   nb_m;

    const int bi = blockIdx.x;                   // b*A_MAX + i
    const int b = bi / A_MAX;
    const int i = bi % A_MAX;
    const int tid = threadIdx.x;
    const int cnt = atom_counts[b];
    float* orow = out + (size_t)bi * REPTOT;

    // whole-block early exit for padded atoms (block-uniform, before barriers)
    if (i >= cnt) {
        for (int t = tid; t < REPTOT; t += 256) orow[t] = 0.0f;
        return;
    }

    // ---- Phase A (wave 0): compacted neighbor list + species indexing ----
    if (tid < 64) {
        const float xi = X[(b * A_MAX + i) * 3 + 0];
        const float yi = X[(b * A_MAX + i) * 3 + 1];
        const float zi = X[(b * A_MAX + i) * 3 + 2];

        bool flag = false;
        float dx = 0.f, dy = 0.f, dz = 0.f, r = 1.f;
        int zj = 0;
        if (tid < A_MAX && tid < cnt) {
            dx = xi - X[(b * A_MAX + tid) * 3 + 0];
            dy = yi - X[(b * A_MAX + tid) * 3 + 1];
            dz = zi - X[(b * A_MAX + tid) * 3 + 2];
            zj = Z[b * A_MAX + tid];
            r = __builtin_amdgcn_sqrtf(dx * dx + dy * dy + dz * dz);
            flag = (tid != i) && (r < RCUT_F);
        }
        const unsigned long long ms0 = __ballot(flag && zj == 0);
        const unsigned long long ms1 = __ballot(flag && zj == 1);
        const unsigned long long ms2 = __ballot(flag && zj == 2);
        const unsigned long long ms3 = __ballot(flag && zj == 3);
        const unsigned long long mask = ms0 | ms1 | ms2 | ms3;
        if (flag) {
            const unsigned long long below = (1ull << tid) - 1ull;
            const int pos = __popcll(mask & below);
            nb_dx[pos] = dx; nb_dy[pos] = dy; nb_dz[pos] = dz;
            nb_r[pos]  = r;  nb_r2[pos] = r * r;
            nb_rinv[pos] = __builtin_amdgcn_rcpf(r);
            nb_z[pos]  = zj;
            const unsigned long long msp = (zj == 0) ? ms0 : (zj == 1) ? ms1
                                         : (zj == 2) ? ms2 : ms3;
            nb_si[pos] = __popcll(msp & below);  // index within own species
            const float fc = 0.5f * (__cosf(PI_F * r * (1.0f / RCUT_F)) + 1.0f);
            const float lr = __logf(r);
            const float s2 = log1pf(ETA2_F / (r * r));
            nb_fc[pos]   = fc;
            nb_mu[pos]   = lr - 0.5f * s2;
            nb_i2s2[pos] = 0.5f * __builtin_amdgcn_rcpf(s2);
            nb_pref[pos] = fc * __expf(-1.8f * lr) *
                           __builtin_amdgcn_rcpf(__builtin_amdgcn_sqrtf(s2) * SQRT_2PI_F);
        }
        if (tid == 0) {
            cnt_s[0] = (int)__popcll(ms0);
            cnt_s[1] = (int)__popcll(ms1);
            cnt_s[2] = (int)__popcll(ms2);
            cnt_s[3] = (int)__popcll(ms3);
            nb_m = (int)__popcll(mask);
        }
    }
    __syncthreads();                             // barrier 1: nb_* / cnt_s ready

    const int m  = nb_m;
    const int c0 = cnt_s[0], c1 = cnt_s[1], c2 = cnt_s[2], c3 = cnt_s[3];
    // named bucket sizes, p-order: (0,0)(0,1)(0,2)(0,3)(1,1)(1,2)(1,3)(2,2)(2,3)(3,3)
    const int S0 = (c0 * (c0 - 1)) >> 1;
    const int S1 = c0 * c1, S2 = c0 * c2, S3 = c0 * c3;
    const int S4 = (c1 * (c1 - 1)) >> 1;
    const int S5 = c1 * c2, S6 = c1 * c3;
    const int S7 = (c2 * (c2 - 1)) >> 1;
    const int S8 = c2 * c3;
    const int ntrip = m * (m - 1) / 2;

    // ---- Phase B: geometry once per triplet, analytic scatter to sorted slot ----
    for (int t = tid; t < ntrip; t += 256) {
        int a, c;
        decode_tri(t, m, a, c);

        const float rij = nb_r[a], rik = nb_r[c];
        const float r2ij = nb_r2[a], r2ik = nb_r2[c];
        const float rinv_a = nb_rinv[a], rinv_c = nb_rinv[c];
        const float djx = nb_dx[a], djy = nb_dy[a], djz = nb_dz[a];
        const float dkx = nb_dx[c], dky = nb_dy[c], dkz = nb_dz[c];

        float cosi = (djx * dkx + djy * dky + djz * dkz) * rinv_a * rinv_c;
        cosi = fminf(1.0f, fmaxf(-1.0f, cosi));

        // REFERENCE SEMANTICS: r_jk clamps to 1.0 when (j,k) not within cutoff
        const float ex = dkx - djx, ey = dky - djy, ez = dkz - djz;
        const float rjk2 = ex * ex + ey * ey + ez * ez;
        const float rjk = __builtin_amdgcn_sqrtf(rjk2);
        const bool w_jk = (rjk < RCUT_F);
        const float rjke  = w_jk ? rjk : 1.0f;
        const float rjke2 = w_jk ? rjk2 : 1.0f;
        const float rinv_jk = w_jk ? __builtin_amdgcn_rcpf(rjk) : 1.0f;

        const float cosj = (r2ij + rjke2 - r2ik) * 0.5f * rinv_a * rinv_jk;
        const float cosk = (r2ik + rjke2 - r2ij) * 0.5f * rinv_c * rinv_jk;

        const float ksi = W3_F * (1.0f + 3.0f * cosi * cosj * cosk)
                        * __expf(-0.57f * __logf(rij * rik * rjke));
        const float w  = ksi * nb_fc[a] * nb_fc[c];
        const float s1v = fmaxf(1.0f - cosi * cosi, 0.0f);

        // bucket + analytic within-bucket rank (bijective by construction)
        const int za = nb_z[a], zc = nb_z[c];
        const int ia = nb_si[a], ic = nb_si[c];
        const int pmn = min(za, zc), pmx = max(za, zc);
        const int p = (pmn * (2 * NSPEC - pmn - 1)) / 2 + pmx;
        int rank;
        if (za == zc) {
            const int cs = (za == 0) ? c0 : (za == 1) ? c1 : (za == 2) ? c2 : c3;
            rank = ia * cs - ((ia * (ia + 1)) >> 1) + (ic - ia - 1);  // ia<ic
        } else {
            const int cmx = (pmx == 0) ? c0 : (pmx == 1) ? c1 : (pmx == 2) ? c2 : c3;
            const int iu = (za < zc) ? ia : ic;  // member of the smaller species
            const int iv = (za < zc) ? ic : ia;  // member of the larger species
            rank = iu * cmx + iv;
        }
        int slot = rank;                          // + exclusive prefix of bucket sizes
        slot += (p > 0) ? S0 : 0;  slot += (p > 1) ? S1 : 0;
        slot += (p > 2) ? S2 : 0;  slot += (p > 3) ? S3 : 0;
        slot += (p > 4) ? S4 : 0;  slot += (p > 5) ? S5 : 0;
        slot += (p > 6) ? S6 : 0;  slot += (p > 7) ? S7 : 0;
        slot += (p > 8) ? S8 : 0;

        trip_wc[slot] = w * cosi;
        trip_ws[slot] = w * __builtin_amdgcn_sqrtf(s1v);
        trip_d[slot]  = 0.5f * (rij + rik);
    }
    __syncthreads();                             // barrier 2: payload sorted

    // ---- Phase C (tid<200): one (p,l) bucket walk each; tail: 2-body ----
    if (tid < NPAIRS * NRS3) {
        const int p = tid / NRS3;
        const int l = tid % NRS3;
        const float Rl = 0.3f * (float)(l + 1);  // RS3[l]
        int s0 = 0;
        s0 += (p > 0) ? S0 : 0;  s0 += (p > 1) ? S1 : 0;
        s0 += (p > 2) ? S2 : 0;  s0 += (p > 3) ? S3 : 0;
        s0 += (p > 4) ? S4 : 0;  s0 += (p > 5) ? S5 : 0;
        s0 += (p > 6) ? S6 : 0;  s0 += (p > 7) ? S7 : 0;
        s0 += (p > 8) ? S8 : 0;
        const int sz = (p == 0) ? S0 : (p == 1) ? S1 : (p == 2) ? S2
                     : (p == 3) ? S3 : (p == 4) ? S4 : (p == 5) ? S5
                     : (p == 6) ? S6 : (p == 7) ? S7 : (p == 8) ? S8
                     : (ntrip - s0);             // p==9: remainder
        const int s1 = s0 + sz;

        float ac0 = 0.0f, as0 = 0.0f, ac1 = 0.0f, as1 = 0.0f;
        int s = s0;
        for (; s + 1 < s1; s += 2) {             // ILP-2 dual accumulators
            const float d0 = trip_d[s],     d1 = trip_d[s + 1];
            const float dd0 = d0 - Rl,      dd1 = d1 - Rl;
            const float e0 = __expf(-ETA3_F * dd0 * dd0);
            const float e1 = __expf(-ETA3_F * dd1 * dd1);
            ac0 += trip_wc[s] * e0;     as0 += trip_ws[s] * e0;
            ac1 += trip_wc[s + 1] * e1; as1 += trip_ws[s + 1] * e1;
        }
        if (s < s1) {
            const float dd = trip_d[s] - Rl;
            const float e = __expf(-ETA3_F * dd * dd);
            ac0 += trip_wc[s] * e;  as0 += trip_ws[s] * e;
        }
        orow[REP2 + p * (NRS3 * 2) + l * 2 + 0] = ac0 + ac1;
        orow[REP2 + p * (NRS3 * 2) + l * 2 + 1] = as0 + as1;
    } else {
        // ---- 2-body on threads 200..255 (56 threads, 96 outputs) ----
        for (int t2 = tid - 200; t2 < REP2; t2 += 56) {
            const int sp = t2 / NRS2;
            const int n = t2 % NRS2;
            const float Rn = 0.25f * (float)(n + 1);   // RS2[n]
            const float logRn = __logf(Rn);
            float acc = 0.0f;
            for (int a = 0; a < m; ++a) {
                if (nb_z[a] == sp) {
                    const float dmu = logRn - nb_mu[a];
                    acc += nb_pref[a] * __expf(-dmu * dmu * nb_i2s2[a]);
                }
            }
            orow[t2] = acc * __builtin_amdgcn_rcpf(Rn);
        }
    }
}

extern "C" void kernel_launch(void* const* d_in, const int* in_sizes, int n_in,
                              void* d_out, int out_size, void* d_ws, size_t ws_size,
                              hipStream_t stream) {
    const float* X           = (const float*)d_in[0];
    const int*   Z           = (const int*)d_in[1];
    // d_in[2] = atomIDs, d_in[3] = molIDs (unused by reference math)
    const int*   atom_counts = (const int*)d_in[4];
    float* out = (float*)d_out;

    fchl_kernel<<<B_MOL * A_MAX, 256, 0, stream>>>(X, Z, atom_counts, out);
}

// Round 6
// 72.233 us; speedup vs baseline: 1.6842x; 1.0186x over previous
//
#include <hip/hip_runtime.h>
#include <math.h>

#define B_MOL 64
#define A_MAX 48
#define NSPEC 4
#define NRS2 24
#define NRS3 20
#define NPAIRS 10
#define REP2 (NSPEC * NRS2)        // 96
#define REP3 (NPAIRS * NRS3 * 2)   // 400
#define REPTOT (REP2 + REP3)       // 496
#define TRIP_CAP 1084              // >= 47*46/2 = 1081

#define RCUT_F 6.0f
#define ETA2_F 0.32f
#define ETA3_F 2.7f
#define PI_F 3.14159265358979323846f
#define W3_F 12.4225780586f        // sqrt(2.7/pi)*13.4
#define SQRT_2PI_F 2.5066282746310002f

// closed-form triplet decode: t -> (a, c), a < c < m, row-major over a
__device__ __forceinline__ void decode_tri(int t, int m, int& a_out, int& c_out) {
    const float fm = (float)(2 * m - 1);
    const float disc = fm * fm - 8.0f * (float)t;   // <= 8649, integer-exact in f32
    const float sq = __builtin_amdgcn_sqrtf(disc);
    int a = (int)((fm - sq) * 0.5f);
    if (a < 0) a = 0;
    while (a > 0 && (a * (2 * m - 1 - a)) / 2 > t) --a;
    while (((a + 1) * (2 * m - 1 - (a + 1))) / 2 <= t) ++a;
    a_out = a;
    c_out = t - (a * (2 * m - 1 - a)) / 2 + a + 1;
}

// 256 threads / atom, ONE barrier:
//   Phase A: executed REDUNDANTLY by all 4 waves (wave-local ballots; LDS
//     writes are benign identical-value races; m,c0..c3 stay in per-wave
//     SGPRs). Removes barrier-1 and the 3-idle-wave serialization. Also
//     builds snb[] = species-grouped neighbor positions (from the same
//     ballots, free).
//   Waves 0-2: triplet geometry once per triplet, analytic bucket scatter
//     (zero atomics) into float4 trip4[].
//   Wave 3 (concurrent): 2-body via snb[] -> exactly c_sp iters per output
//     (4x fewer than predicated full-m loop). Hidden under Phase B.
//   barrier; Phase C: 200 threads = one (p,l) bucket walk each, ds_read_b128
//     payload, ILP-2 accumulators.
// LDS ~19.4 KB -> 8 blocks/CU (32 waves).
__global__ __launch_bounds__(256, 8) void fchl_kernel(
    const float* __restrict__ X, const int* __restrict__ Z,
    const int* __restrict__ atom_counts, float* __restrict__ out)
{
    __shared__ float nb_dx[A_MAX], nb_dy[A_MAX], nb_dz[A_MAX];
    __shared__ float nb_r[A_MAX], nb_r2[A_MAX], nb_rinv[A_MAX];
    __shared__ float nb_fc[A_MAX], nb_mu[A_MAX], nb_i2s2[A_MAX], nb_pref[A_MAX];
    __shared__ int   nb_z[A_MAX], nb_si[A_MAX], snb[A_MAX];
    __shared__ float4 trip4[TRIP_CAP];           // (wc, ws, d, --)

    const int bi = blockIdx.x;                   // b*A_MAX + i
    const int b = bi / A_MAX;
    const int i = bi % A_MAX;
    const int tid = threadIdx.x;
    const int lane = tid & 63;
    const int cnt = atom_counts[b];
    float* orow = out + (size_t)bi * REPTOT;

    // whole-block early exit for padded atoms (block-uniform, before barrier)
    if (i >= cnt) {
        for (int t = tid; t < REPTOT; t += 256) orow[t] = 0.0f;
        return;
    }

    // ---- Phase A: ALL waves, redundantly (identical results per wave) ----
    const float xi = X[(b * A_MAX + i) * 3 + 0];
    const float yi = X[(b * A_MAX + i) * 3 + 1];
    const float zi = X[(b * A_MAX + i) * 3 + 2];

    bool flag = false;
    float dx = 0.f, dy = 0.f, dz = 0.f, r = 1.f;
    int zj = 0;
    if (lane < A_MAX && lane < cnt) {
        dx = xi - X[(b * A_MAX + lane) * 3 + 0];
        dy = yi - X[(b * A_MAX + lane) * 3 + 1];
        dz = zi - X[(b * A_MAX + lane) * 3 + 2];
        zj = Z[b * A_MAX + lane];
        r = __builtin_amdgcn_sqrtf(dx * dx + dy * dy + dz * dz);
        flag = (lane != i) && (r < RCUT_F);
    }
    const unsigned long long ms0 = __ballot(flag && zj == 0);
    const unsigned long long ms1 = __ballot(flag && zj == 1);
    const unsigned long long ms2 = __ballot(flag && zj == 2);
    const unsigned long long ms3 = __ballot(flag && zj == 3);
    const unsigned long long mask = ms0 | ms1 | ms2 | ms3;
    const int m  = (int)__popcll(mask);
    const int c0 = (int)__popcll(ms0), c1 = (int)__popcll(ms1);
    const int c2 = (int)__popcll(ms2), c3 = (int)__popcll(ms3);

    if (flag) {
        const unsigned long long below = (1ull << lane) - 1ull;
        const int pos = __popcll(mask & below);
        nb_dx[pos] = dx; nb_dy[pos] = dy; nb_dz[pos] = dz;
        nb_r[pos]  = r;  nb_r2[pos] = r * r;
        nb_rinv[pos] = __builtin_amdgcn_rcpf(r);
        nb_z[pos]  = zj;
        const unsigned long long msp = (zj == 0) ? ms0 : (zj == 1) ? ms1
                                     : (zj == 2) ? ms2 : ms3;
        const int si = __popcll(msp & below);    // index within own species
        nb_si[pos] = si;
        const int ss = (zj == 0) ? 0 : (zj == 1) ? c0
                     : (zj == 2) ? (c0 + c1) : (c0 + c1 + c2);
        snb[ss + si] = pos;                      // species-grouped position list
        const float fc = 0.5f * (__cosf(PI_F * r * (1.0f / RCUT_F)) + 1.0f);
        const float lr = __logf(r);
        const float s2 = log1pf(ETA2_F / (r * r));
        nb_fc[pos]   = fc;
        nb_mu[pos]   = lr - 0.5f * s2;
        nb_i2s2[pos] = 0.5f * __builtin_amdgcn_rcpf(s2);
        nb_pref[pos] = fc * __expf(-1.8f * lr) *
                       __builtin_amdgcn_rcpf(__builtin_amdgcn_sqrtf(s2) * SQRT_2PI_F);
    }
    __builtin_amdgcn_wave_barrier();             // compile-time order: A before reads

    // named bucket sizes, p-order: (0,0)(0,1)(0,2)(0,3)(1,1)(1,2)(1,3)(2,2)(2,3)(3,3)
    const int S0 = (c0 * (c0 - 1)) >> 1;
    const int S1 = c0 * c1, S2 = c0 * c2, S3 = c0 * c3;
    const int S4 = (c1 * (c1 - 1)) >> 1;
    const int S5 = c1 * c2, S6 = c1 * c3;
    const int S7 = (c2 * (c2 - 1)) >> 1;
    const int S8 = c2 * c3;
    const int ntrip = m * (m - 1) / 2;

    if (tid >= 192) {
        // ---- wave 3: 2-body via species-grouped list (runs under Phase B) ----
        for (int t2 = lane; t2 < REP2; t2 += 64) {
            const int sp = t2 / NRS2;
            const int n  = t2 % NRS2;
            const float Rn = 0.25f * (float)(n + 1);   // RS2[n]
            const float logRn = __logf(Rn);
            const int ss = (sp == 0) ? 0 : (sp == 1) ? c0
                         : (sp == 2) ? (c0 + c1) : (c0 + c1 + c2);
            const int ce = ss + ((sp == 0) ? c0 : (sp == 1) ? c1
                               : (sp == 2) ? c2 : c3);
            float acc = 0.0f;
            for (int a2 = ss; a2 < ce; ++a2) {
                const int idx = snb[a2];
                const float dmu = logRn - nb_mu[idx];
                acc += nb_pref[idx] * __expf(-dmu * dmu * nb_i2s2[idx]);
            }
            orow[t2] = acc * __builtin_amdgcn_rcpf(Rn);
        }
    } else {
        // ---- waves 0-2: geometry once per triplet, analytic scatter ----
        for (int t = tid; t < ntrip; t += 192) {
            int a, c;
            decode_tri(t, m, a, c);

            const float rij = nb_r[a], rik = nb_r[c];
            const float r2ij = nb_r2[a], r2ik = nb_r2[c];
            const float rinv_a = nb_rinv[a], rinv_c = nb_rinv[c];
            const float djx = nb_dx[a], djy = nb_dy[a], djz = nb_dz[a];
            const float dkx = nb_dx[c], dky = nb_dy[c], dkz = nb_dz[c];

            float cosi = (djx * dkx + djy * dky + djz * dkz) * rinv_a * rinv_c;
            cosi = fminf(1.0f, fmaxf(-1.0f, cosi));

            // REFERENCE SEMANTICS: r_jk clamps to 1.0 when (j,k) not within cutoff
            const float ex = dkx - djx, ey = dky - djy, ez = dkz - djz;
            const float rjk2 = ex * ex + ey * ey + ez * ez;
            const float rjk = __builtin_amdgcn_sqrtf(rjk2);
            const bool w_jk = (rjk < RCUT_F);
            const float rjke  = w_jk ? rjk : 1.0f;
            const float rjke2 = w_jk ? rjk2 : 1.0f;
            const float rinv_jk = w_jk ? __builtin_amdgcn_rcpf(rjk) : 1.0f;

            const float cosj = (r2ij + rjke2 - r2ik) * 0.5f * rinv_a * rinv_jk;
            const float cosk = (r2ik + rjke2 - r2ij) * 0.5f * rinv_c * rinv_jk;

            const float ksi = W3_F * (1.0f + 3.0f * cosi * cosj * cosk)
                            * __expf(-0.57f * __logf(rij * rik * rjke));
            const float w  = ksi * nb_fc[a] * nb_fc[c];
            const float s1v = fmaxf(1.0f - cosi * cosi, 0.0f);

            // bucket + analytic within-bucket rank (bijective by construction)
            const int za = nb_z[a], zc = nb_z[c];
            const int ia = nb_si[a], ic = nb_si[c];
            const int pmn = min(za, zc), pmx = max(za, zc);
            const int p = (pmn * (2 * NSPEC - pmn - 1)) / 2 + pmx;
            int rank;
            if (za == zc) {
                const int cs = (za == 0) ? c0 : (za == 1) ? c1 : (za == 2) ? c2 : c3;
                rank = ia * cs - ((ia * (ia + 1)) >> 1) + (ic - ia - 1);  // ia<ic
            } else {
                const int cmx = (pmx == 0) ? c0 : (pmx == 1) ? c1 : (pmx == 2) ? c2 : c3;
                const int iu = (za < zc) ? ia : ic;  // member of the smaller species
                const int iv = (za < zc) ? ic : ia;  // member of the larger species
                rank = iu * cmx + iv;
            }
            int slot = rank;                      // + exclusive prefix of bucket sizes
            slot += (p > 0) ? S0 : 0;  slot += (p > 1) ? S1 : 0;
            slot += (p > 2) ? S2 : 0;  slot += (p > 3) ? S3 : 0;
            slot += (p > 4) ? S4 : 0;  slot += (p > 5) ? S5 : 0;
            slot += (p > 6) ? S6 : 0;  slot += (p > 7) ? S7 : 0;
            slot += (p > 8) ? S8 : 0;

            trip4[slot] = make_float4(w * cosi,
                                      w * __builtin_amdgcn_sqrtf(s1v),
                                      0.5f * (rij + rik), 0.0f);
        }
    }
    __syncthreads();                             // the ONLY block-wide barrier

    // ---- Phase C (tid<200): one (p,l) bucket walk each, b128 payload ----
    if (tid < NPAIRS * NRS3) {
        const int p = tid / NRS3;
        const int l = tid % NRS3;
        const float Rl = 0.3f * (float)(l + 1);  // RS3[l]
        int s0 = 0;
        s0 += (p > 0) ? S0 : 0;  s0 += (p > 1) ? S1 : 0;
        s0 += (p > 2) ? S2 : 0;  s0 += (p > 3) ? S3 : 0;
        s0 += (p > 4) ? S4 : 0;  s0 += (p > 5) ? S5 : 0;
        s0 += (p > 6) ? S6 : 0;  s0 += (p > 7) ? S7 : 0;
        s0 += (p > 8) ? S8 : 0;
        const int sz = (p == 0) ? S0 : (p == 1) ? S1 : (p == 2) ? S2
                     : (p == 3) ? S3 : (p == 4) ? S4 : (p == 5) ? S5
                     : (p == 6) ? S6 : (p == 7) ? S7 : (p == 8) ? S8
                     : (ntrip - s0);             // p==9: remainder
        const int s1 = s0 + sz;

        float ac0 = 0.0f, as0 = 0.0f, ac1 = 0.0f, as1 = 0.0f;
        int s = s0;
        for (; s + 1 < s1; s += 2) {             // ILP-2 dual accumulators
            const float4 t0 = trip4[s];
            const float4 t1 = trip4[s + 1];
            const float dd0 = t0.z - Rl, dd1 = t1.z - Rl;
            const float e0 = __expf(-ETA3_F * dd0 * dd0);
            const float e1 = __expf(-ETA3_F * dd1 * dd1);
            ac0 += t0.x * e0;  as0 += t0.y * e0;
            ac1 += t1.x * e1;  as1 += t1.y * e1;
        }
        if (s < s1) {
            const float4 t0 = trip4[s];
            const float dd = t0.z - Rl;
            const float e = __expf(-ETA3_F * dd * dd);
            ac0 += t0.x * e;  as0 += t0.y * e;
        }
        orow[REP2 + p * (NRS3 * 2) + l * 2 + 0] = ac0 + ac1;
        orow[REP2 + p * (NRS3 * 2) + l * 2 + 1] = as0 + as1;
    }
}

extern "C" void kernel_launch(void* const* d_in, const int* in_sizes, int n_in,
                              void* d_out, int out_size, void* d_ws, size_t ws_size,
                              hipStream_t stream) {
    const float* X           = (const float*)d_in[0];
    const int*   Z           = (const int*)d_in[1];
    // d_in[2] = atomIDs, d_in[3] = molIDs (unused by reference math)
    const int*   atom_counts = (const int*)d_in[4];
    float* out = (float*)d_out;

    fchl_kernel<<<B_MOL * A_MAX, 256, 0, stream>>>(X, Z, atom_counts, out);
}